// Round 5
// baseline (260.695 us; speedup 1.0000x reference)
//
#include <hip/hip_runtime.h>
#include <math.h>

#define GXD 128
#define GYD 128
#define GZD 16
#define BD  4
#define VTOT (BD*GXD*GYD*GZD)   // 1,048,576 voxels
#define EPSV 1e-4f

#define DNX 64
#define DNY 64
#define DNZ 8
#define NDOWN (BD*DNX*DNY*DNZ)  // 131,072 rows

#define NXCD 8
#define CHUNK 4096
#define ACC_GRID 2048

// ---------------------------------------------------------------------------
// XCD-local atomic accumulation.
// Voxel partition p = vidx>>17 = (b<<1)|(cx>>6). Blocks discover their XCD
// (s_getreg HW_REG_XCC_ID), dynamically share the point stream among the
// blocks of that XCD via a per-XCD ticket counter, and only accumulate points
// whose voxel partition equals their XCD. All atomics to a partition are thus
// issued from a single XCD -> its (non-cross-coherent) L2 is a legal
// coherence point -> workgroup-scope atomics (executed at local TCC, not the
// slow device-coherent memory-side path) are correct. Kernel-end release
// writes the dirty table back for the eig kernel.
//
// Per-voxel payload: one u64, all 10 moments packed (same as R4):
//   yz:6 @0  xz:6 @6  xy:6 @12 (scale 24, biased +h_i*h_j)
//   zz:5 @18 yy:5 @23 xx:5 @28 (scale 32, centered coords a = l-h)
//   sz:8 @33 (scale 16)  sy:9 @41  sx:9 @50 (scale 32)  cnt:5 @59
// ---------------------------------------------------------------------------

__global__ void __launch_bounds__(256)
accum_kernel(const float4* __restrict__ pts,
             const float* __restrict__ vsz,
             unsigned long long* __restrict__ table,
             unsigned int* __restrict__ tickets, int n) {
    int xcc;
    asm volatile("s_getreg_b32 %0, hwreg(HW_REG_XCC_ID)" : "=s"(xcc));
    xcc &= (NXCD - 1);

    float vx = vsz[0], vy = vsz[1], vz = vsz[2];
    float ivx = 1.0f / vx, ivy = 1.0f / vy, ivz = 1.0f / vz;
    float hx = 0.5f * vx, hy = 0.5f * vy, hz = 0.5f * vz;

    __shared__ unsigned int sc;
    for (;;) {
        __syncthreads();               // protect sc against reuse
        if (threadIdx.x == 0) sc = atomicAdd(tickets + xcc, 1u);  // agent scope, rare
        __syncthreads();
        int base = (int)sc * CHUNK;
        if (base >= n) break;
        int lim = min(n - base, CHUNK);
        for (int j = (int)threadIdx.x; j < lim; j += 256) {
            float4 p = pts[base + j];
            int b = (int)p.x;
            int cx = min(max((int)floorf(p.y * ivx), 0), GXD - 1);
            int part = (b << 1) | (cx >> 6);
            if (part != xcc) continue;           // another XCD owns this voxel
            int cy = min(max((int)floorf(p.z * ivy), 0), GYD - 1);
            int cz = min(max((int)floorf(p.w * ivz), 0), GZD - 1);
            int vidx = ((b * GXD + cx) * GYD + cy) * GZD + cz;
            float lx = fminf(fmaxf(p.y - (float)cx * vx, 0.0f), vx);
            float ly = fminf(fmaxf(p.z - (float)cy * vy, 0.0f), vy);
            float lz = fminf(fmaxf(p.w - (float)cz * vz, 0.0f), vz);
            float ax = lx - hx, ay = ly - hy, az = lz - hz;

            unsigned long long q =
                (1ULL << 59)
              | ((unsigned long long)(unsigned int)(lx * 32.0f + 0.5f) << 50)
              | ((unsigned long long)(unsigned int)(ly * 32.0f + 0.5f) << 41)
              | ((unsigned long long)(unsigned int)(lz * 16.0f + 0.5f) << 33)
              | ((unsigned long long)(unsigned int)(ax * ax * 32.0f + 0.5f) << 28)
              | ((unsigned long long)(unsigned int)(ay * ay * 32.0f + 0.5f) << 23)
              | ((unsigned long long)(unsigned int)(az * az * 32.0f + 0.5f) << 18)
              | ((unsigned long long)(unsigned int)((ax * ay + hx * hy) * 24.0f + 0.5f) << 12)
              | ((unsigned long long)(unsigned int)((ax * az + hx * hz) * 24.0f + 0.5f) << 6)
              |  (unsigned long long)(unsigned int)((ay * az + hy * hz) * 24.0f + 0.5f);

            // XCD-local atomic: executes in this XCD's L2 (partition is
            // 1 MB -> L2-resident), not at the device-coherent point.
            __hip_atomic_fetch_add(&table[vidx], q, __ATOMIC_RELAXED,
                                   __HIP_MEMORY_SCOPE_WORKGROUP);
        }
    }
}

__device__ inline void eigh3(float A[3][3], float w[3], float Q[3][3]) {
    #pragma unroll
    for (int r = 0; r < 3; ++r)
        #pragma unroll
        for (int c = 0; c < 3; ++c)
            Q[r][c] = (r == c) ? 1.0f : 0.0f;

    const int PP[3] = {0, 0, 1};
    const int QQ[3] = {1, 2, 2};
    for (int sweep = 0; sweep < 4; ++sweep) {
        #pragma unroll
        for (int k = 0; k < 3; ++k) {
            int p = PP[k], q = QQ[k];
            float apq = A[p][q];
            if (apq == 0.0f) continue;
            float app = A[p][p], aqq = A[q][q];
            float theta = 0.5f * (aqq - app) / apq;
            float t = 1.0f / (fabsf(theta) + sqrtf(theta * theta + 1.0f));
            if (theta < 0.0f) t = -t;
            float c = rsqrtf(t * t + 1.0f);
            float s = t * c;
            int r = 3 - p - q;
            float arp = A[r][p], arq = A[r][q];
            A[p][p] = app - t * apq;
            A[q][q] = aqq + t * apq;
            A[p][q] = 0.0f; A[q][p] = 0.0f;
            float nrp = c * arp - s * arq;
            float nrq = s * arp + c * arq;
            A[r][p] = nrp; A[p][r] = nrp;
            A[r][q] = nrq; A[q][r] = nrq;
            #pragma unroll
            for (int m = 0; m < 3; ++m) {
                float vp = Q[m][p], vq = Q[m][q];
                Q[m][p] = c * vp - s * vq;
                Q[m][q] = s * vp + c * vq;
            }
        }
    }
    w[0] = A[0][0]; w[1] = A[1][1]; w[2] = A[2][2];
    #pragma unroll
    for (int pass = 0; pass < 3; ++pass) {
        int a = (pass == 1) ? 1 : 0;
        int bcol = a + 1;
        if (w[a] > w[bcol]) {
            float tw = w[a]; w[a] = w[bcol]; w[bcol] = tw;
            #pragma unroll
            for (int m = 0; m < 3; ++m) {
                float tv = Q[m][a]; Q[m][a] = Q[m][bcol]; Q[m][bcol] = tv;
            }
        }
    }
}

__global__ void __launch_bounds__(256)
eig_kernel(const unsigned long long* __restrict__ ws,
           const float* __restrict__ vsz,
           float* __restrict__ out_vals,
           float* __restrict__ out_vecs) {
    __shared__ float sv[256 * 3];
    __shared__ float se[256 * 9];
    int t = threadIdx.x;
    int v = blockIdx.x * 256 + t;

    unsigned long long q = ws[v];
    unsigned int cnt = (unsigned int)(q >> 59);
    float hx = 0.5f * vsz[0], hy = 0.5f * vsz[1], hz = 0.5f * vsz[2];
    float A[3][3];
    if (cnt == 0u) {
        A[0][0] = EPSV;        A[0][1] = 0.0f;        A[0][2] = 0.0f;
        A[1][0] = 0.0f;        A[1][1] = 2.0f * EPSV; A[1][2] = 0.0f;
        A[2][0] = 0.0f;        A[2][1] = 0.0f;        A[2][2] = 3.0f * EPSV;
    } else {
        float inv = 1.0f / (float)cnt;
        float fc  = (float)cnt;
        float slx = (float)((q >> 50) & 0x1FFULL) * (1.0f / 32.0f);
        float sly = (float)((q >> 41) & 0x1FFULL) * (1.0f / 32.0f);
        float slz = (float)((q >> 33) & 0xFFULL)  * (1.0f / 16.0f);
        float sxx = (float)((q >> 28) & 0x1FULL)  * (1.0f / 32.0f);
        float syy = (float)((q >> 23) & 0x1FULL)  * (1.0f / 32.0f);
        float szz = (float)((q >> 18) & 0x1FULL)  * (1.0f / 32.0f);
        float sxy = (float)((q >> 12) & 0x3FULL)  * (1.0f / 24.0f) - fc * hx * hy;
        float sxz = (float)((q >> 6)  & 0x3FULL)  * (1.0f / 24.0f) - fc * hx * hz;
        float syz = (float)(q & 0x3FULL)          * (1.0f / 24.0f) - fc * hy * hz;
        float mx = slx * inv - hx;
        float my = sly * inv - hy;
        float mz = slz * inv - hz;
        A[0][0] = sxx * inv - mx * mx + EPSV;
        A[0][1] = sxy * inv - mx * my;
        A[0][2] = sxz * inv - mx * mz;
        A[1][1] = syy * inv - my * my + 2.0f * EPSV;
        A[1][2] = syz * inv - my * mz;
        A[2][2] = szz * inv - mz * mz + 3.0f * EPSV;
        A[1][0] = A[0][1]; A[2][0] = A[0][2]; A[2][1] = A[1][2];
    }
    float w[3], Q[3][3];
    eigh3(A, w, Q);

    sv[3 * t + 0] = w[0]; sv[3 * t + 1] = w[1]; sv[3 * t + 2] = w[2];
    #pragma unroll
    for (int r = 0; r < 3; ++r)
        #pragma unroll
        for (int c = 0; c < 3; ++c)
            se[9 * t + r * 3 + c] = Q[r][c];
    __syncthreads();

    float* ov = out_vals + (size_t)blockIdx.x * 768;
    #pragma unroll
    for (int j = 0; j < 3; ++j)
        ov[t + 256 * j] = sv[t + 256 * j];
    float* oe = out_vecs + (size_t)blockIdx.x * 2304;
    #pragma unroll
    for (int j = 0; j < 9; ++j)
        oe[t + 256 * j] = se[t + 256 * j];
}

__global__ void bcenter_kernel(const float* __restrict__ vsz,
                               float4* __restrict__ out) {
    int i = blockIdx.x * blockDim.x + threadIdx.x;
    if (i >= NDOWN) return;
    int dz = i & (DNZ - 1);
    int t = i >> 3;
    int dy = t & (DNY - 1);
    t >>= 6;
    int dx = t & (DNX - 1);
    int b = t >> 6;
    float vx = vsz[0], vy = vsz[1], vz = vsz[2];
    out[i] = make_float4((float)b,
                         ((float)(2 * dx) + 0.5f) * vx,
                         ((float)(2 * dy) + 0.5f) * vy,
                         ((float)(2 * dz) + 0.5f) * vz);
}

extern "C" void kernel_launch(void* const* d_in, const int* in_sizes, int n_in,
                              void* d_out, int out_size, void* d_ws, size_t ws_size,
                              hipStream_t stream) {
    const float* pts = (const float*)d_in[0];
    const float* vsz = (const float*)d_in[1];
    float* out = (float*)d_out;
    unsigned long long* table = (unsigned long long*)d_ws;
    unsigned int* tickets = (unsigned int*)((char*)d_ws + (size_t)VTOT * 8);
    int n = in_sizes[0] / 4;

    // zero table (8 MB) + 8 ticket counters in one shot
    hipMemsetAsync(d_ws, 0, (size_t)VTOT * 8 + NXCD * sizeof(unsigned int), stream);

    accum_kernel<<<ACC_GRID, 256, 0, stream>>>(
        (const float4*)pts, vsz, table, tickets, n);

    float* out_vals = out + NDOWN * 4;
    float* out_vecs = out_vals + (size_t)3 * VTOT;
    eig_kernel<<<VTOT / 256, 256, 0, stream>>>(table, vsz, out_vals, out_vecs);

    bcenter_kernel<<<(NDOWN + 255) / 256, 256, 0, stream>>>(
        vsz, (float4*)out);
}

// Round 6
// 185.180 us; speedup vs baseline: 1.4078x; 1.4078x over previous
//
#include <hip/hip_runtime.h>
#include <math.h>

#define GXD 128
#define GYD 128
#define GZD 16
#define BD  4
#define VTOT (BD*GXD*GYD*GZD)   // 1,048,576 voxels
#define EPSV 1e-4f

#define DNX 64
#define DNY 64
#define DNZ 8
#define NDOWN (BD*DNX*DNY*DNZ)  // 131,072 rows

// ---------------------------------------------------------------------------
// accum: R4 structure (measured floor: scattered fabric atomics are a fixed
// ~22 Gop/s pipe regardless of layout/scope — R1-R5; 1 op/point = 90 us).
// Per-voxel payload: one u64, all 10 moments packed:
//   yz:6 @0  xz:6 @6  xy:6 @12 (scale 24, biased +h_i*h_j, centered coords)
//   zz:5 @18 yy:5 @23 xx:5 @28 (scale 32, centered coords a = l-h)
//   sz:8 @33 (scale 16)  sy:9 @41  sx:9 @50 (scale 32)  cnt:5 @59
// ---------------------------------------------------------------------------

__global__ void accum_kernel(const float4* __restrict__ pts,
                             const float* __restrict__ vsz,
                             unsigned long long* __restrict__ ws, int n) {
    int i = blockIdx.x * blockDim.x + threadIdx.x;
    if (i >= n) return;
    float4 p = pts[i];
    float vx = vsz[0], vy = vsz[1], vz = vsz[2];
    int b = (int)p.x;
    int cx = min(max((int)floorf(p.y / vx), 0), GXD - 1);
    int cy = min(max((int)floorf(p.z / vy), 0), GYD - 1);
    int cz = min(max((int)floorf(p.w / vz), 0), GZD - 1);
    int vidx = ((b * GXD + cx) * GYD + cy) * GZD + cz;
    float lx = fminf(fmaxf(p.y - (float)cx * vx, 0.0f), vx);
    float ly = fminf(fmaxf(p.z - (float)cy * vy, 0.0f), vy);
    float lz = fminf(fmaxf(p.w - (float)cz * vz, 0.0f), vz);
    float hx = 0.5f * vx, hy = 0.5f * vy, hz = 0.5f * vz;
    float ax = lx - hx, ay = ly - hy, az = lz - hz;

    unsigned long long q =
        (1ULL << 59)
      | ((unsigned long long)(unsigned int)(lx * 32.0f + 0.5f) << 50)
      | ((unsigned long long)(unsigned int)(ly * 32.0f + 0.5f) << 41)
      | ((unsigned long long)(unsigned int)(lz * 16.0f + 0.5f) << 33)
      | ((unsigned long long)(unsigned int)(ax * ax * 32.0f + 0.5f) << 28)
      | ((unsigned long long)(unsigned int)(ay * ay * 32.0f + 0.5f) << 23)
      | ((unsigned long long)(unsigned int)(az * az * 32.0f + 0.5f) << 18)
      | ((unsigned long long)(unsigned int)((ax * ay + hx * hy) * 24.0f + 0.5f) << 12)
      | ((unsigned long long)(unsigned int)((ax * az + hx * hz) * 24.0f + 0.5f) << 6)
      |  (unsigned long long)(unsigned int)((ay * az + hy * hz) * 24.0f + 0.5f);

    atomicAdd(ws + vidx, q);
}

// One Jacobi rotation on pair (p,q), fully scalarized, branchless, fast
// hardware rcp/rsq/sqrt (rel err ~1e-7 — noise vs the 2.02 threshold).
// APP,AQQ,APQ: diagonal & pivot entries.  ARP,ARQ: the third row's entries.
// (P0,P1,P2)/(Q0,Q1,Q2): eigvec matrix columns p and q.
#define JROT(APP, AQQ, APQ, ARP, ARQ, P0, P1, P2, Q0, Q1, Q2)                 \
    {                                                                          \
        float apq_ = APQ;                                                      \
        bool z_ = (apq_ == 0.0f);                                              \
        float dn_ = z_ ? 1.0f : apq_;                                          \
        float th_ = 0.5f * (AQQ - APP) * __builtin_amdgcn_rcpf(dn_);           \
        float tt_ = __builtin_amdgcn_rcpf(                                     \
            fabsf(th_) + __builtin_amdgcn_sqrtf(th_ * th_ + 1.0f));            \
        tt_ = (th_ < 0.0f) ? -tt_ : tt_;                                       \
        tt_ = z_ ? 0.0f : tt_;                                                 \
        float cc_ = __builtin_amdgcn_rsqf(tt_ * tt_ + 1.0f);                   \
        float ss_ = tt_ * cc_;                                                 \
        APP -= tt_ * apq_;                                                     \
        AQQ += tt_ * apq_;                                                     \
        APQ = 0.0f;                                                            \
        float u_ = ARP, v_ = ARQ;                                              \
        ARP = cc_ * u_ - ss_ * v_;                                             \
        ARQ = ss_ * u_ + cc_ * v_;                                             \
        u_ = P0; v_ = Q0; P0 = cc_ * u_ - ss_ * v_; Q0 = ss_ * u_ + cc_ * v_;  \
        u_ = P1; v_ = Q1; P1 = cc_ * u_ - ss_ * v_; Q1 = ss_ * u_ + cc_ * v_;  \
        u_ = P2; v_ = Q2; P2 = cc_ * u_ - ss_ * v_; Q2 = ss_ * u_ + cc_ * v_;  \
    }

#define CSWAP(WA, WB, A0, A1, A2, B0, B1, B2)                                  \
    if (WA > WB) {                                                             \
        float t_;                                                              \
        t_ = WA; WA = WB; WB = t_;                                             \
        t_ = A0; A0 = B0; B0 = t_;                                             \
        t_ = A1; A1 = B1; B1 = t_;                                             \
        t_ = A2; A2 = B2; B2 = t_;                                             \
    }

__global__ void __launch_bounds__(256)
eig_kernel(const unsigned long long* __restrict__ ws,
           const float* __restrict__ vsz,
           float* __restrict__ out_vals,
           float* __restrict__ out_vecs,
           float4* __restrict__ out_bc) {
    __shared__ float sv[256 * 3];
    __shared__ float se[256 * 9];
    int t = threadIdx.x;
    int v = blockIdx.x * 256 + t;

    float vx = vsz[0], vy = vsz[1], vz = vsz[2];
    float hx = 0.5f * vx, hy = 0.5f * vy, hz = 0.5f * vz;

    // fused bcenter (first NDOWN threads; exact, data-independent)
    if (v < NDOWN) {
        int dz = v & (DNZ - 1);
        int u = v >> 3;
        int dy = u & (DNY - 1);
        u >>= 6;
        int dx = u & (DNX - 1);
        int bb = u >> 6;
        out_bc[v] = make_float4((float)bb,
                                ((float)(2 * dx) + 0.5f) * vx,
                                ((float)(2 * dy) + 0.5f) * vy,
                                ((float)(2 * dz) + 0.5f) * vz);
    }

    unsigned long long q = ws[v];
    unsigned int cnt = (unsigned int)(q >> 59);
    bool emp = (cnt == 0u);
    float inv = __builtin_amdgcn_rcpf((float)max(cnt, 1u));
    float fc  = (float)cnt;
    float slx = (float)((q >> 50) & 0x1FFULL) * (1.0f / 32.0f);
    float sly = (float)((q >> 41) & 0x1FFULL) * (1.0f / 32.0f);
    float slz = (float)((q >> 33) & 0xFFULL)  * (1.0f / 16.0f);
    float sxx = (float)((q >> 28) & 0x1FULL)  * (1.0f / 32.0f);
    float syy = (float)((q >> 23) & 0x1FULL)  * (1.0f / 32.0f);
    float szz = (float)((q >> 18) & 0x1FULL)  * (1.0f / 32.0f);
    float sxy = (float)((q >> 12) & 0x3FULL)  * (1.0f / 24.0f) - fc * hx * hy;
    float sxz = (float)((q >> 6)  & 0x3FULL)  * (1.0f / 24.0f) - fc * hx * hz;
    float syz = (float)(q & 0x3FULL)          * (1.0f / 24.0f) - fc * hy * hz;
    float mx = slx * inv - hx;
    float my = sly * inv - hy;
    float mz = slz * inv - hz;
    float a00 = emp ? EPSV        : sxx * inv - mx * mx + EPSV;
    float a01 = emp ? 0.0f        : sxy * inv - mx * my;
    float a02 = emp ? 0.0f        : sxz * inv - mx * mz;
    float a11 = emp ? 2.0f * EPSV : syy * inv - my * my + 2.0f * EPSV;
    float a12 = emp ? 0.0f        : syz * inv - my * mz;
    float a22 = emp ? 3.0f * EPSV : szz * inv - mz * mz + 3.0f * EPSV;

    float q00 = 1.0f, q01 = 0.0f, q02 = 0.0f;
    float q10 = 0.0f, q11 = 1.0f, q12 = 0.0f;
    float q20 = 0.0f, q21 = 0.0f, q22 = 1.0f;

    #pragma unroll
    for (int sweep = 0; sweep < 3; ++sweep) {
        // (p,q) = (0,1), r=2: third-row entries A[2][0]=a02, A[2][1]=a12
        JROT(a00, a11, a01, a02, a12, q00, q10, q20, q01, q11, q21);
        // (p,q) = (0,2), r=1: A[1][0]=a01, A[1][2]=a12
        JROT(a00, a22, a02, a01, a12, q00, q10, q20, q02, q12, q22);
        // (p,q) = (1,2), r=0: A[0][1]=a01, A[0][2]=a02
        JROT(a11, a22, a12, a01, a02, q01, q11, q21, q02, q12, q22);
    }

    // sort eigvals ascending, carrying eigvec columns
    CSWAP(a00, a11, q00, q10, q20, q01, q11, q21);
    CSWAP(a11, a22, q01, q11, q21, q02, q12, q22);
    CSWAP(a00, a11, q00, q10, q20, q01, q11, q21);

    sv[3 * t + 0] = a00; sv[3 * t + 1] = a11; sv[3 * t + 2] = a22;
    se[9 * t + 0] = q00; se[9 * t + 1] = q01; se[9 * t + 2] = q02;
    se[9 * t + 3] = q10; se[9 * t + 4] = q11; se[9 * t + 5] = q12;
    se[9 * t + 6] = q20; se[9 * t + 7] = q21; se[9 * t + 8] = q22;
    __syncthreads();

    // coalesced writeback
    float* ov = out_vals + (size_t)blockIdx.x * 768;
    #pragma unroll
    for (int j = 0; j < 3; ++j)
        ov[t + 256 * j] = sv[t + 256 * j];
    float* oe = out_vecs + (size_t)blockIdx.x * 2304;
    #pragma unroll
    for (int j = 0; j < 9; ++j)
        oe[t + 256 * j] = se[t + 256 * j];
}

extern "C" void kernel_launch(void* const* d_in, const int* in_sizes, int n_in,
                              void* d_out, int out_size, void* d_ws, size_t ws_size,
                              hipStream_t stream) {
    const float* pts = (const float*)d_in[0];
    const float* vsz = (const float*)d_in[1];
    float* out = (float*)d_out;
    unsigned long long* ws = (unsigned long long*)d_ws;
    int n = in_sizes[0] / 4;

    // zero the 1-u64 voxel table (8 MB)
    hipMemsetAsync(d_ws, 0, (size_t)VTOT * sizeof(unsigned long long), stream);

    int tb = 256;
    accum_kernel<<<(n + tb - 1) / tb, tb, 0, stream>>>(
        (const float4*)pts, vsz, ws, n);

    float* out_vals = out + NDOWN * 4;
    float* out_vecs = out_vals + (size_t)3 * VTOT;
    eig_kernel<<<VTOT / tb, tb, 0, stream>>>(
        ws, vsz, out_vals, out_vecs, (float4*)out);
}